// Round 3
// baseline (303.918 us; speedup 1.0000x reference)
//
#include <hip/hip_runtime.h>
#include <hip/hip_bf16.h>
#include <math.h>

// Problem constants
#define T_ 4
#define N_ 16
#define F_ 6
#define L_ 1024
#define A_ 21
#define K_ 20
#define U_ 256
#define LOUT 1005            // L - K + 1
#define NIMG 384             // T*N*F
#define SZ_S (T_*N_*U_)      // 16384
#define SZ_R (K_*A_*U_)      // 107520
#define XBROWS 1056          // padded rows per image (>= 896+64+15+48+19+1 = 1043)

typedef __attribute__((ext_vector_type(8))) short short8;   // 8 bf16 (4 VGPR)
typedef __attribute__((ext_vector_type(4))) float f32x4;    // 4 f32 acc

__device__ __forceinline__ unsigned short f2bf(float f) {
  unsigned int u = __float_as_uint(f);
  u += 0x7FFFu + ((u >> 16) & 1u);   // round to nearest even
  return (unsigned short)(u >> 16);
}

__device__ __forceinline__ void atomicMaxF(float* addr, float val) {
  if (val >= 0.f) atomicMax((int*)addr, __float_as_int(val));
  else            atomicMin((unsigned int*)addr, __float_as_uint(val));
}

// S init to -inf, R (fp32, exact) into d_out, Rt = bf16 R transposed+padded
// to [kk][u][32] in workspace (MFMA A operand).
__global__ void prep_kernel(const float* __restrict__ P_logit,
                            const float* __restrict__ Q,
                            float* __restrict__ out,
                            unsigned short* __restrict__ Rt) {
  int tid = blockIdx.x * blockDim.x + threadIdx.x;
  if (tid < SZ_S) out[tid] = -INFINITY;
  if (tid >= K_ * U_) return;
  int k = tid / U_;
  int u = tid - k * U_;
  const float* pl = P_logit + (size_t)k * A_ * U_ + u;
  float v[A_];
  float m = -INFINITY;
#pragma unroll
  for (int a = 0; a < A_; ++a) { v[a] = pl[(size_t)a * U_]; m = fmaxf(m, v[a]); }
  float s = 0.f;
#pragma unroll
  for (int a = 0; a < A_; ++a) { v[a] = expf(v[a] - m); s += v[a]; }
  float qs = 0.f;
#pragma unroll
  for (int a = 0; a < A_; ++a) qs += Q[a];
  float eps = qs * (1.0f / A_);
  float invs = 1.f / s;
  float* Rout = out + SZ_S;
  unsigned short* rt = Rt + (size_t)(k * U_ + u) * 32;
#pragma unroll
  for (int a = 0; a < A_; ++a) {
    float r = logf(fmaxf(v[a] * invs / Q[a], eps));
    Rout[(size_t)(k * A_ + a) * U_ + u] = r;
    rt[a] = f2bf(r);
  }
#pragma unroll
  for (int a = A_; a < 32; ++a) rt[a] = 0;
}

// X (fp32 [n][1024][21]) -> Xb (bf16 [n][1056][32], zero-padded in both dims).
// One thread per 2 output columns; uint (bf16x2) stores, 64 B per 16 lanes.
__global__ void xconv_kernel(const float* __restrict__ X,
                             unsigned int* __restrict__ Xb32) {
  int t = blockIdx.x * blockDim.x + threadIdx.x;
  if (t >= NIMG * XBROWS * 16) return;
  int c2 = (t & 15) * 2;
  int rl = t >> 4;                 // n*XBROWS + l
  int l  = rl % XBROWS;
  int n  = rl / XBROWS;
  float v0 = 0.f, v1 = 0.f;
  if (l < L_) {
    const float* xr = X + ((size_t)n * L_ + l) * A_;
    if (c2 < A_)     v0 = xr[c2];
    if (c2 + 1 < A_) v1 = xr[c2 + 1];
  }
  unsigned int o = (unsigned int)f2bf(v0) | ((unsigned int)f2bf(v1) << 16);
  Xb32[(size_t)rl * 16 + (t & 15)] = o;
}

// Conv as 20 accumulated GEMMs. A = R (M=u), B = X (N=l), D = Z[u][l] tiles.
// NO LDS, NO barriers: B-fragments read directly from padded bf16 Xb; each
// wave instruction reads 1 KB contiguous (16 rows x 64 B), L1-resident
// (9.4 KB window re-read ~34x). A-fragments (R) are L2-resident (320 KB).
// Block tile: 128 l x 128 u, 4 waves (2x2), wave 64u x 64l.
__global__ __launch_bounds__(256, 4) void conv_kernel(
    const unsigned short* __restrict__ Xb,
    const unsigned short* __restrict__ Rt,
    float* __restrict__ out) {
  const int n  = blockIdx.z;
  const int l0 = blockIdx.y * 128;
  const int u0 = blockIdx.x * 128;

  const int wid  = threadIdx.x >> 6;
  const int lane = threadIdx.x & 63;
  const int wl   = wid >> 1;
  const int wu   = wid & 1;
  const int fl   = lane & 15;           // frag row (A: u) / col (B: l)
  const int fk   = (lane >> 4) << 3;    // frag k-offset (a dim)

  f32x4 acc[4][4];                      // [ut][lt]
#pragma unroll
  for (int ut = 0; ut < 4; ++ut)
#pragma unroll
    for (int lt = 0; lt < 4; ++lt)
      acc[ut][lt] = (f32x4){0.f, 0.f, 0.f, 0.f};

  const unsigned short* xb =
      Xb + ((size_t)n * XBROWS + l0 + wl * 64 + fl) * 32 + fk;
  const unsigned short* rbase = Rt + ((size_t)(u0 + wu * 64 + fl)) * 32 + fk;

#pragma unroll 2
  for (int kk = 0; kk < K_; ++kk) {
    short8 xfr[4], rfr[4];
    const unsigned short* rbk = rbase + (size_t)kk * (U_ * 32);
#pragma unroll
    for (int lt = 0; lt < 4; ++lt)
      xfr[lt] = *(const short8*)(xb + (size_t)(kk + lt * 16) * 32);
#pragma unroll
    for (int ut = 0; ut < 4; ++ut)
      rfr[ut] = *(const short8*)(rbk + ut * (16 * 32));
#pragma unroll
    for (int ut = 0; ut < 4; ++ut)
#pragma unroll
      for (int lt = 0; lt < 4; ++lt)
        acc[ut][lt] = __builtin_amdgcn_mfma_f32_16x16x32_bf16(
            rfr[ut], xfr[lt], acc[ut][lt], 0, 0, 0);
  }

  // Epilogue: D layout col(l)=lane&15, row(u)=(lane>>4)*4+reg -> lane holds
  // 4 consecutive u at fixed l => float4 store into row-major Z[l][u].
  float* Z = out + SZ_S + SZ_R;
  const int ug = (lane >> 4) << 2;
  float pmax[4][4];
#pragma unroll
  for (int ut = 0; ut < 4; ++ut)
#pragma unroll
    for (int r = 0; r < 4; ++r) pmax[ut][r] = -INFINITY;

#pragma unroll
  for (int lt = 0; lt < 4; ++lt) {
    const int l = l0 + wl * 64 + lt * 16 + fl;
    if (l < LOUT) {
      float* zrow = Z + ((size_t)n * LOUT + l) * U_ + u0 + wu * 64 + ug;
#pragma unroll
      for (int ut = 0; ut < 4; ++ut) {
        f32x4 v = acc[ut][lt];
        *(f32x4*)(zrow + ut * 16) = v;
#pragma unroll
        for (int r = 0; r < 4; ++r) pmax[ut][r] = fmaxf(pmax[ut][r], v[r]);
      }
    }
  }

#pragma unroll
  for (int off = 1; off < 16; off <<= 1)
#pragma unroll
    for (int ut = 0; ut < 4; ++ut)
#pragma unroll
      for (int r = 0; r < 4; ++r)
        pmax[ut][r] = fmaxf(pmax[ut][r], __shfl_xor(pmax[ut][r], off));

  if (fl == 0) {
    const int tn = n / F_;
    float* Sp = out + (size_t)tn * U_ + u0 + wu * 64 + ug;
#pragma unroll
    for (int ut = 0; ut < 4; ++ut)
#pragma unroll
      for (int r = 0; r < 4; ++r)
        atomicMaxF(Sp + ut * 16 + r, pmax[ut][r]);
  }
}

// Fallback (ws too small for Xb): round-2 staged variant, WITHOUT nt stores.
#define BM 128
#define WROWS (BM + K_ - 1)   // 147
#define XSTR 40

__global__ __launch_bounds__(256, 4) void conv_staged_kernel(
    const float* __restrict__ X,
    const unsigned short* __restrict__ Rt,
    float* __restrict__ out) {
  __shared__ unsigned short Xs[WROWS * XSTR];
  const int n  = blockIdx.z;
  const int l0 = blockIdx.y * BM;
  const int u0 = blockIdx.x * 128;

  const float* Xn = X + (size_t)n * (L_ * A_);
  for (int idx = threadIdx.x; idx < WROWS * 32; idx += 256) {
    int r = idx >> 5, c = idx & 31;
    int l = l0 + r;
    float v = (c < A_ && l < L_) ? Xn[l * A_ + c] : 0.f;
    Xs[r * XSTR + c] = f2bf(v);
  }
  __syncthreads();

  const int wid  = threadIdx.x >> 6;
  const int lane = threadIdx.x & 63;
  const int wl   = wid >> 1;
  const int wu   = wid & 1;
  const int fl   = lane & 15;
  const int fk   = (lane >> 4) << 3;

  f32x4 acc[4][4];
#pragma unroll
  for (int ut = 0; ut < 4; ++ut)
#pragma unroll
    for (int lt = 0; lt < 4; ++lt)
      acc[ut][lt] = (f32x4){0.f, 0.f, 0.f, 0.f};

  const unsigned short* rbase = Rt + ((size_t)(u0 + wu * 64 + fl)) * 32 + fk;
  const int arow = wl * 64 + fl;

#pragma unroll 2
  for (int kk = 0; kk < K_; ++kk) {
    short8 xfr[4], rfr[4];
    const unsigned short* rbk = rbase + (size_t)kk * (U_ * 32);
#pragma unroll
    for (int lt = 0; lt < 4; ++lt)
      xfr[lt] = *(const short8*)(&Xs[(arow + lt * 16 + kk) * XSTR + fk]);
#pragma unroll
    for (int ut = 0; ut < 4; ++ut)
      rfr[ut] = *(const short8*)(rbk + ut * (16 * 32));
#pragma unroll
    for (int ut = 0; ut < 4; ++ut)
#pragma unroll
      for (int lt = 0; lt < 4; ++lt)
        acc[ut][lt] = __builtin_amdgcn_mfma_f32_16x16x32_bf16(
            rfr[ut], xfr[lt], acc[ut][lt], 0, 0, 0);
  }

  float* Z = out + SZ_S + SZ_R;
  const int ug = (lane >> 4) << 2;
  float pmax[4][4];
#pragma unroll
  for (int ut = 0; ut < 4; ++ut)
#pragma unroll
    for (int r = 0; r < 4; ++r) pmax[ut][r] = -INFINITY;

#pragma unroll
  for (int lt = 0; lt < 4; ++lt) {
    const int l = l0 + wl * 64 + lt * 16 + fl;
    if (l < LOUT) {
      float* zrow = Z + ((size_t)n * LOUT + l) * U_ + u0 + wu * 64 + ug;
#pragma unroll
      for (int ut = 0; ut < 4; ++ut) {
        f32x4 v = acc[ut][lt];
        *(f32x4*)(zrow + ut * 16) = v;
#pragma unroll
        for (int r = 0; r < 4; ++r) pmax[ut][r] = fmaxf(pmax[ut][r], v[r]);
      }
    }
  }

#pragma unroll
  for (int off = 1; off < 16; off <<= 1)
#pragma unroll
    for (int ut = 0; ut < 4; ++ut)
#pragma unroll
      for (int r = 0; r < 4; ++r)
        pmax[ut][r] = fmaxf(pmax[ut][r], __shfl_xor(pmax[ut][r], off));

  if (fl == 0) {
    const int tn = n / F_;
    float* Sp = out + (size_t)tn * U_ + u0 + wu * 64 + ug;
#pragma unroll
    for (int ut = 0; ut < 4; ++ut)
#pragma unroll
      for (int r = 0; r < 4; ++r)
        atomicMaxF(Sp + ut * 16 + r, pmax[ut][r]);
  }
}

extern "C" void kernel_launch(void* const* d_in, const int* in_sizes, int n_in,
                              void* d_out, int out_size, void* d_ws, size_t ws_size,
                              hipStream_t stream) {
  const float* X       = (const float*)d_in[0];
  const float* P_logit = (const float*)d_in[1];
  const float* Q       = (const float*)d_in[2];
  float* out = (float*)d_out;
  unsigned short* Rt = (unsigned short*)d_ws;            // 320 KB
  const size_t rt_bytes = (size_t)K_ * U_ * 32 * 2;      // 327680
  unsigned short* Xb = (unsigned short*)((char*)d_ws + rt_bytes);
  const size_t need = rt_bytes + (size_t)NIMG * XBROWS * 32 * 2;  // ~26.3 MB

  hipLaunchKernelGGL(prep_kernel, dim3(64), dim3(256), 0, stream,
                     P_logit, Q, out, Rt);
  dim3 grid(2, 8, NIMG);
  if (ws_size >= need) {
    int xthreads = NIMG * XBROWS * 16;
    hipLaunchKernelGGL(xconv_kernel, dim3((xthreads + 255) / 256), dim3(256),
                       0, stream, X, (unsigned int*)Xb);
    hipLaunchKernelGGL(conv_kernel, grid, dim3(256), 0, stream, Xb, Rt, out);
  } else {
    hipLaunchKernelGGL(conv_staged_kernel, grid, dim3(256), 0, stream,
                       X, Rt, out);
  }
}

// Round 4
// 199.036 us; speedup vs baseline: 1.5269x; 1.5269x over previous
//
#include <hip/hip_runtime.h>
#include <hip/hip_bf16.h>
#include <math.h>

// Problem constants
#define T_ 4
#define N_ 16
#define F_ 6
#define L_ 1024
#define A_ 21
#define K_ 20
#define U_ 256
#define LOUT 1005            // L - K + 1
#define NIMG 384             // T*N*F
#define SZ_S (T_*N_*U_)      // 16384
#define SZ_R (K_*A_*U_)      // 107520
#define XBROWS 1056          // padded rows per image

typedef __attribute__((ext_vector_type(8))) short short8;   // 8 bf16 (4 VGPR)
typedef __attribute__((ext_vector_type(4))) float f32x4;    // 4 f32 acc

__device__ __forceinline__ unsigned short f2bf(float f) {
  unsigned int u = __float_as_uint(f);
  u += 0x7FFFu + ((u >> 16) & 1u);   // round to nearest even
  return (unsigned short)(u >> 16);
}

__device__ __forceinline__ void atomicMaxF(float* addr, float val) {
  if (val >= 0.f) atomicMax((int*)addr, __float_as_int(val));
  else            atomicMin((unsigned int*)addr, __float_as_uint(val));
}

// Async global->LDS, 16B per lane. LDS dest is wave-uniform base + lane*16.
__device__ __forceinline__ void gload_lds16(const void* g, void* l) {
  __builtin_amdgcn_global_load_lds(
      (const __attribute__((address_space(1))) void*)g,
      (__attribute__((address_space(3))) void*)l, 16, 0, 0);
}

// S init to -inf, R (fp32, exact) into d_out, Rt = bf16 R transposed+padded
// to [kk][u][32] in workspace (MFMA A operand).
__global__ void prep_kernel(const float* __restrict__ P_logit,
                            const float* __restrict__ Q,
                            float* __restrict__ out,
                            unsigned short* __restrict__ Rt) {
  int tid = blockIdx.x * blockDim.x + threadIdx.x;
  if (tid < SZ_S) out[tid] = -INFINITY;
  if (tid >= K_ * U_) return;
  int k = tid / U_;
  int u = tid - k * U_;
  const float* pl = P_logit + (size_t)k * A_ * U_ + u;
  float v[A_];
  float m = -INFINITY;
#pragma unroll
  for (int a = 0; a < A_; ++a) { v[a] = pl[(size_t)a * U_]; m = fmaxf(m, v[a]); }
  float s = 0.f;
#pragma unroll
  for (int a = 0; a < A_; ++a) { v[a] = expf(v[a] - m); s += v[a]; }
  float qs = 0.f;
#pragma unroll
  for (int a = 0; a < A_; ++a) qs += Q[a];
  float eps = qs * (1.0f / A_);
  float invs = 1.f / s;
  float* Rout = out + SZ_S;
  unsigned short* rt = Rt + (size_t)(k * U_ + u) * 32;
#pragma unroll
  for (int a = 0; a < A_; ++a) {
    float r = logf(fmaxf(v[a] * invs / Q[a], eps));
    Rout[(size_t)(k * A_ + a) * U_ + u] = r;
    rt[a] = f2bf(r);
  }
#pragma unroll
  for (int a = A_; a < 32; ++a) rt[a] = 0;
}

// X (fp32 [n][1024][21]) -> Xb (bf16 [n][1056][32], zero-padded both dims).
__global__ void xconv_kernel(const float* __restrict__ X,
                             unsigned int* __restrict__ Xb32) {
  int t = blockIdx.x * blockDim.x + threadIdx.x;
  if (t >= NIMG * XBROWS * 16) return;
  int c2 = (t & 15) * 2;
  int rl = t >> 4;                 // n*XBROWS + l
  int l  = rl % XBROWS;
  int n  = rl / XBROWS;
  float v0 = 0.f, v1 = 0.f;
  if (l < L_) {
    const float* xr = X + ((size_t)n * L_ + l) * A_;
    if (c2 < A_)     v0 = xr[c2];
    if (c2 + 1 < A_) v1 = xr[c2 + 1];
  }
  unsigned int o = (unsigned int)f2bf(v0) | ((unsigned int)f2bf(v1) << 16);
  Xb32[(size_t)rl * 16 + (t & 15)] = o;
}

// Conv as 20 accumulated GEMMs (one tap per K-step). A = R (M=u), B = X (N=l).
// T3+T4 pipeline: X window (12 KB) staged once via global_load_lds; per-tap
// R slice (8 KB) staged 3 taps ahead into a 4-buffer ring, counted vmcnt(4)
// (never drained to 0 in the main loop), one raw s_barrier per tap.
// Block tile: 128 l x 128 u, 4 waves (2x2), wave 64u x 64l.
#define BM 128
#define XCH 12    // X chunks (1 KB each) -> 192 LDS rows
#define RCH 8     // R chunks per tap (8 KB)
#define NBUF 4

__global__ __launch_bounds__(256, 3) void conv_kernel(
    const unsigned short* __restrict__ Xb,
    const unsigned short* __restrict__ Rt,
    float* __restrict__ out) {
  __shared__ unsigned short lds_x[XCH * 512];    // 12 KB
  __shared__ unsigned short lds_r[NBUF * 4096];  // 32 KB (4 bufs x 8 KB)

  const int n  = blockIdx.z;
  const int l0 = blockIdx.y * BM;
  const int u0 = blockIdx.x * 128;
  const int wid  = threadIdx.x >> 6;
  const int lane = threadIdx.x & 63;

  const char* xsrc = (const char*)Xb + (size_t)n * XBROWS * 64;
  const char* rsrc = (const char*)Rt + (size_t)u0 * 64;
  const int img_max = XBROWS * 64 - 1024;        // clamp for last l-tile

  // ---- prologue: stage X (3 chunks/wave) + R taps 0,1,2 (2 chunks/wave each)
#pragma unroll
  for (int r = 0; r < 3; ++r) {
    int c = wid + r * 4;
    int off = l0 * 64 + c * 1024;
    if (off > img_max) off = img_max;            // dup of last KB, rows unused
    gload_lds16(xsrc + off + lane * 16, (char*)lds_x + c * 1024);
  }
#pragma unroll
  for (int kk = 0; kk < 3; ++kk) {
#pragma unroll
    for (int r = 0; r < 2; ++r) {
      int c = wid * 2 + r;
      gload_lds16(rsrc + (size_t)kk * (U_ * 64) + c * 1024 + lane * 16,
                  (char*)lds_r + (kk & (NBUF - 1)) * 8192 + c * 1024);
    }
  }
  // own X + R0 landed (outstanding <= R1,R2 = 4), then certify block-wide
  asm volatile("s_waitcnt vmcnt(4)" ::: "memory");
  __builtin_amdgcn_s_barrier();

  const int wl = wid >> 1;
  const int wu = wid & 1;
  const int fl = lane & 15;            // frag row (A: u) / col (B: l)
  const int fk = (lane >> 4) << 3;     // frag k-offset (a dim), shorts

  f32x4 acc[4][4];                     // [ut][lt]
#pragma unroll
  for (int ut = 0; ut < 4; ++ut)
#pragma unroll
    for (int lt = 0; lt < 4; ++lt)
      acc[ut][lt] = (f32x4){0.f, 0.f, 0.f, 0.f};

  const int xrow = wl * 64 + fl;       // + kk + lt*16
  const int urow = wu * 64 + fl;       // + ut*16

#pragma unroll 1
  for (int kk = 0; kk < K_; ++kk) {
    // ds_read fragments for tap kk (buffer certified by prev-iter barrier)
    short8 xfr[4], rfr[4];
    const unsigned short* xb = lds_x + (size_t)(xrow + kk) * 32 + fk;
    const unsigned short* rb = lds_r + (kk & (NBUF - 1)) * 4096 + urow * 32 + fk;
#pragma unroll
    for (int lt = 0; lt < 4; ++lt) xfr[lt] = *(const short8*)(xb + lt * 512);
#pragma unroll
    for (int ut = 0; ut < 4; ++ut) rfr[ut] = *(const short8*)(rb + ut * 512);

    // stage tap kk+3 into ring (overwrites buf read in iter kk-1, barrier-safe)
    if (kk + 3 < K_) {
#pragma unroll
      for (int r = 0; r < 2; ++r) {
        int c = wid * 2 + r;
        gload_lds16(rsrc + (size_t)(kk + 3) * (U_ * 64) + c * 1024 + lane * 16,
                    (char*)lds_r + ((kk + 3) & (NBUF - 1)) * 8192 + c * 1024);
      }
    }

#pragma unroll
    for (int ut = 0; ut < 4; ++ut)
#pragma unroll
      for (int lt = 0; lt < 4; ++lt)
        acc[ut][lt] = __builtin_amdgcn_mfma_f32_16x16x32_bf16(
            rfr[ut], xfr[lt], acc[ut][lt], 0, 0, 0);

    // certify tap kk+1 (outstanding {kk+1,kk+2,kk+3} = 6 -> wait to 4)
    if (kk < K_ - 3) asm volatile("s_waitcnt vmcnt(4)" ::: "memory");
    else             asm volatile("s_waitcnt vmcnt(0)" ::: "memory");
    __builtin_amdgcn_s_barrier();
  }

  // Epilogue: D layout col(l)=lane&15, row(u)=(lane>>4)*4+reg -> lane holds
  // 4 consecutive u at fixed l => float4 store into row-major Z[l][u].
  float* Z = out + SZ_S + SZ_R;
  const int ug = (lane >> 4) << 2;
  float pmax[4][4];
#pragma unroll
  for (int ut = 0; ut < 4; ++ut)
#pragma unroll
    for (int r = 0; r < 4; ++r) pmax[ut][r] = -INFINITY;

#pragma unroll
  for (int lt = 0; lt < 4; ++lt) {
    const int l = l0 + wl * 64 + lt * 16 + fl;
    if (l < LOUT) {
      float* zrow = Z + ((size_t)n * LOUT + l) * U_ + u0 + wu * 64 + ug;
#pragma unroll
      for (int ut = 0; ut < 4; ++ut) {
        f32x4 v = acc[ut][lt];
        *(f32x4*)(zrow + ut * 16) = v;
#pragma unroll
        for (int r = 0; r < 4; ++r) pmax[ut][r] = fmaxf(pmax[ut][r], v[r]);
      }
    }
  }

#pragma unroll
  for (int off = 1; off < 16; off <<= 1)
#pragma unroll
    for (int ut = 0; ut < 4; ++ut)
#pragma unroll
      for (int r = 0; r < 4; ++r)
        pmax[ut][r] = fmaxf(pmax[ut][r], __shfl_xor(pmax[ut][r], off));

  if (fl == 0) {
    const int tn = n / F_;
    float* Sp = out + (size_t)tn * U_ + u0 + wu * 64 + ug;
#pragma unroll
    for (int ut = 0; ut < 4; ++ut)
#pragma unroll
      for (int r = 0; r < 4; ++r)
        atomicMaxF(Sp + ut * 16 + r, pmax[ut][r]);
  }
}

// Fallback (ws too small for Xb): staged variant reading fp32 X directly.
#define WROWS (BM + K_ - 1)   // 147
#define XSTR 40

__global__ __launch_bounds__(256, 4) void conv_staged_kernel(
    const float* __restrict__ X,
    const unsigned short* __restrict__ Rt,
    float* __restrict__ out) {
  __shared__ unsigned short Xs[WROWS * XSTR];
  const int n  = blockIdx.z;
  const int l0 = blockIdx.y * BM;
  const int u0 = blockIdx.x * 128;

  const float* Xn = X + (size_t)n * (L_ * A_);
  for (int idx = threadIdx.x; idx < WROWS * 32; idx += 256) {
    int r = idx >> 5, c = idx & 31;
    int l = l0 + r;
    float v = (c < A_ && l < L_) ? Xn[l * A_ + c] : 0.f;
    Xs[r * XSTR + c] = f2bf(v);
  }
  __syncthreads();

  const int wid  = threadIdx.x >> 6;
  const int lane = threadIdx.x & 63;
  const int wl   = wid >> 1;
  const int wu   = wid & 1;
  const int fl   = lane & 15;
  const int fk   = (lane >> 4) << 3;

  f32x4 acc[4][4];
#pragma unroll
  for (int ut = 0; ut < 4; ++ut)
#pragma unroll
    for (int lt = 0; lt < 4; ++lt)
      acc[ut][lt] = (f32x4){0.f, 0.f, 0.f, 0.f};

  const unsigned short* rbase = Rt + ((size_t)(u0 + wu * 64 + fl)) * 32 + fk;
  const int arow = wl * 64 + fl;

#pragma unroll 2
  for (int kk = 0; kk < K_; ++kk) {
    short8 xfr[4], rfr[4];
    const unsigned short* rbk = rbase + (size_t)kk * (U_ * 32);
#pragma unroll
    for (int lt = 0; lt < 4; ++lt)
      xfr[lt] = *(const short8*)(&Xs[(arow + lt * 16 + kk) * XSTR + fk]);
#pragma unroll
    for (int ut = 0; ut < 4; ++ut)
      rfr[ut] = *(const short8*)(rbk + ut * (16 * 32));
#pragma unroll
    for (int ut = 0; ut < 4; ++ut)
#pragma unroll
      for (int lt = 0; lt < 4; ++lt)
        acc[ut][lt] = __builtin_amdgcn_mfma_f32_16x16x32_bf16(
            rfr[ut], xfr[lt], acc[ut][lt], 0, 0, 0);
  }

  float* Z = out + SZ_S + SZ_R;
  const int ug = (lane >> 4) << 2;
  float pmax[4][4];
#pragma unroll
  for (int ut = 0; ut < 4; ++ut)
#pragma unroll
    for (int r = 0; r < 4; ++r) pmax[ut][r] = -INFINITY;

#pragma unroll
  for (int lt = 0; lt < 4; ++lt) {
    const int l = l0 + wl * 64 + lt * 16 + fl;
    if (l < LOUT) {
      float* zrow = Z + ((size_t)n * LOUT + l) * U_ + u0 + wu * 64 + ug;
#pragma unroll
      for (int ut = 0; ut < 4; ++ut) {
        f32x4 v = acc[ut][lt];
        *(f32x4*)(zrow + ut * 16) = v;
#pragma unroll
        for (int r = 0; r < 4; ++r) pmax[ut][r] = fmaxf(pmax[ut][r], v[r]);
      }
    }
  }

#pragma unroll
  for (int off = 1; off < 16; off <<= 1)
#pragma unroll
    for (int ut = 0; ut < 4; ++ut)
#pragma unroll
      for (int r = 0; r < 4; ++r)
        pmax[ut][r] = fmaxf(pmax[ut][r], __shfl_xor(pmax[ut][r], off));

  if (fl == 0) {
    const int tn = n / F_;
    float* Sp = out + (size_t)tn * U_ + u0 + wu * 64 + ug;
#pragma unroll
    for (int ut = 0; ut < 4; ++ut)
#pragma unroll
      for (int r = 0; r < 4; ++r)
        atomicMaxF(Sp + ut * 16 + r, pmax[ut][r]);
  }
}

extern "C" void kernel_launch(void* const* d_in, const int* in_sizes, int n_in,
                              void* d_out, int out_size, void* d_ws, size_t ws_size,
                              hipStream_t stream) {
  const float* X       = (const float*)d_in[0];
  const float* P_logit = (const float*)d_in[1];
  const float* Q       = (const float*)d_in[2];
  float* out = (float*)d_out;
  unsigned short* Rt = (unsigned short*)d_ws;            // 320 KB
  const size_t rt_bytes = (size_t)K_ * U_ * 32 * 2;
  unsigned short* Xb = (unsigned short*)((char*)d_ws + rt_bytes);
  const size_t need = rt_bytes + (size_t)NIMG * XBROWS * 32 * 2;  // ~26.3 MB

  hipLaunchKernelGGL(prep_kernel, dim3(64), dim3(256), 0, stream,
                     P_logit, Q, out, Rt);
  dim3 grid(2, 8, NIMG);
  if (ws_size >= need) {
    int xthreads = NIMG * XBROWS * 16;
    hipLaunchKernelGGL(xconv_kernel, dim3((xthreads + 255) / 256), dim3(256),
                       0, stream, X, (unsigned int*)Xb);
    hipLaunchKernelGGL(conv_kernel, grid, dim3(256), 0, stream, Xb, Rt, out);
  } else {
    hipLaunchKernelGGL(conv_staged_kernel, grid, dim3(256), 0, stream,
                       X, Rt, out);
  }
}

// Round 5
// 187.656 us; speedup vs baseline: 1.6195x; 1.0606x over previous
//
#include <hip/hip_runtime.h>
#include <hip/hip_bf16.h>
#include <math.h>

// Problem constants
#define T_ 4
#define N_ 16
#define F_ 6
#define L_ 1024
#define A_ 21
#define K_ 20
#define U_ 256
#define LOUT 1005            // L - K + 1
#define NIMG 384             // T*N*F
#define SZ_S (T_*N_*U_)      // 16384
#define SZ_R (K_*A_*U_)      // 107520

// Packed-X geometry: row stride 24 shorts (48 B). For output row l, contraction
// slot c maps to tap=c/24, col=c%24 (independent of l) -> contiguous aligned
// K-window of 512 slots (16 MFMA K-steps of 32). Cols 21..23 and tap>=20 are
// zero on the R side.
#define XPR 24               // shorts per packed row
#define XROWS 1056           // padded rows per image
#define NSTEP 16             // K-steps of 32 slots (512 >= 19*24+20+1)
#define RT_SHORTS (NSTEP * U_ * 32)   // 131072 shorts = 256 KB

typedef __attribute__((ext_vector_type(8))) short short8;   // 8 bf16 (4 VGPR)
typedef __attribute__((ext_vector_type(4))) float f32x4;    // 4 f32 acc

__device__ __forceinline__ unsigned short f2bf(float f) {
  unsigned int u = __float_as_uint(f);
  u += 0x7FFFu + ((u >> 16) & 1u);   // round to nearest even
  return (unsigned short)(u >> 16);
}

__device__ __forceinline__ void atomicMaxF(float* addr, float val) {
  if (val >= 0.f) atomicMax((int*)addr, __float_as_int(val));
  else            atomicMin((unsigned int*)addr, __float_as_uint(val));
}

// Async global->LDS, 16B per lane. LDS dest is wave-uniform base + lane*16.
__device__ __forceinline__ void gload_lds16(const void* g, void* l) {
  __builtin_amdgcn_global_load_lds(
      (const __attribute__((address_space(1))) void*)g,
      (__attribute__((address_space(3))) void*)l, 16, 0, 0);
}

// S init to -inf, R (fp32, exact) into d_out, and Rt = bf16 R scattered into
// slot order: Rt[(s>>5)*8192 + u*32 + (s&31)], s = k*24 + a. Pad slots are
// zeroed beforehand by hipMemsetAsync.
__global__ void prep_kernel(const float* __restrict__ P_logit,
                            const float* __restrict__ Q,
                            float* __restrict__ out,
                            unsigned short* __restrict__ Rt) {
  int tid = blockIdx.x * blockDim.x + threadIdx.x;
  if (tid < SZ_S) out[tid] = -INFINITY;
  if (tid >= K_ * U_) return;
  int k = tid / U_;
  int u = tid - k * U_;
  const float* pl = P_logit + (size_t)k * A_ * U_ + u;
  float v[A_];
  float m = -INFINITY;
#pragma unroll
  for (int a = 0; a < A_; ++a) { v[a] = pl[(size_t)a * U_]; m = fmaxf(m, v[a]); }
  float s = 0.f;
#pragma unroll
  for (int a = 0; a < A_; ++a) { v[a] = expf(v[a] - m); s += v[a]; }
  float qs = 0.f;
#pragma unroll
  for (int a = 0; a < A_; ++a) qs += Q[a];
  float eps = qs * (1.0f / A_);
  float invs = 1.f / s;
  float* Rout = out + SZ_S;
#pragma unroll
  for (int a = 0; a < A_; ++a) {
    float r = logf(fmaxf(v[a] * invs / Q[a], eps));
    Rout[(size_t)(k * A_ + a) * U_ + u] = r;
    int sl = k * XPR + a;
    Rt[(size_t)(sl >> 5) * (U_ * 32) + u * 32 + (sl & 31)] = f2bf(r);
  }
}

// X (fp32 [n][1024][21]) -> Xp (bf16 [n][1056][24], zero-padded both dims).
__global__ void xconv_kernel(const float* __restrict__ X,
                             unsigned int* __restrict__ Xp32) {
  int t = blockIdx.x * blockDim.x + threadIdx.x;
  if (t >= NIMG * XROWS * 12) return;
  int w  = t % 12;
  int rl = t / 12;                 // n*XROWS + row
  int row = rl % XROWS;
  int n   = rl / XROWS;
  int c0 = w * 2;
  float v0 = 0.f, v1 = 0.f;
  if (row < L_) {
    const float* xr = X + ((size_t)n * L_ + row) * A_;
    if (c0 < A_)     v0 = xr[c0];
    if (c0 + 1 < A_) v1 = xr[c0 + 1];
  }
  unsigned int o = (unsigned int)f2bf(v0) | ((unsigned int)f2bf(v1) << 16);
  Xp32[(size_t)rl * 12 + w] = o;
}

// Conv as one GEMM: M=u (A=R slots), N=l (B=packed-X window), K=512 (16 steps).
// - X window (8 KB) staged once via global_load_lds; ONE barrier total.
// - R fragments read directly from global (L2-resident 256 KB), pre-swizzled
//   to fragment order, double-buffered one K-step ahead.
// Block tile: 128 l x 128 u, 4 waves (2x2), wave 64u x 64l.
__global__ __launch_bounds__(256, 3) void conv_kernel(
    const unsigned short* __restrict__ Xp,
    const unsigned short* __restrict__ Rt,
    float* __restrict__ out) {
  __shared__ unsigned short lds_x[4096];   // 8192 B: rows l0..l0+170 (need 149)

  const int n  = blockIdx.z;
  const int l0 = blockIdx.y * 128;
  const int u0 = blockIdx.x * 128;
  const int wid  = threadIdx.x >> 6;
  const int lane = threadIdx.x & 63;

  // Stage packed X rows [l0 .. ] : 8 x 1KB chunks (2 per wave).
  const char* xsrc = (const char*)Xp + ((size_t)n * XROWS + l0) * (XPR * 2);
#pragma unroll
  for (int r = 0; r < 2; ++r) {
    int c = wid * 2 + r;
    gload_lds16(xsrc + c * 1024 + lane * 16, (char*)lds_x + c * 1024);
  }
  asm volatile("s_waitcnt vmcnt(0)" ::: "memory");
  __syncthreads();

  const int wl = wid >> 1;
  const int wu = wid & 1;
  const int fl = lane & 15;            // frag row (A: u) / col (B: l)
  const int fj = lane >> 4;            // k sub-chunk (8 shorts each)

  f32x4 acc[4][4];                     // [ut][lt]
#pragma unroll
  for (int ut = 0; ut < 4; ++ut)
#pragma unroll
    for (int lt = 0; lt < 4; ++lt)
      acc[ut][lt] = (f32x4){0.f, 0.f, 0.f, 0.f};

  // R frag base: shorts. frag(step, ut) = rb + step*8192 + ut*512
  const unsigned short* rb =
      Rt + (size_t)(u0 + wu * 64 + fl) * 32 + (fj << 3);
  // X frag base: shorts in LDS. frag(step, lt) at xb + lt*(16*24) + step*32
  const unsigned short* xb = lds_x + (wl * 64 + fl) * XPR + (fj << 3);

  short8 rA[4], rB[4];
#pragma unroll
  for (int ut = 0; ut < 4; ++ut)
    rA[ut] = *(const short8*)(rb + ut * 512);

#pragma unroll 1
  for (int s = 0; s < NSTEP; s += 2) {
    short8 xf[4];
    // prefetch step s+1 R frags
#pragma unroll
    for (int ut = 0; ut < 4; ++ut)
      rB[ut] = *(const short8*)(rb + (size_t)(s + 1) * 8192 + ut * 512);
    // step s
#pragma unroll
    for (int lt = 0; lt < 4; ++lt)
      xf[lt] = *(const short8*)(xb + lt * (16 * XPR) + s * 32);
#pragma unroll
    for (int ut = 0; ut < 4; ++ut)
#pragma unroll
      for (int lt = 0; lt < 4; ++lt)
        acc[ut][lt] = __builtin_amdgcn_mfma_f32_16x16x32_bf16(
            rA[ut], xf[lt], acc[ut][lt], 0, 0, 0);
    // prefetch step s+2 R frags
    if (s + 2 < NSTEP) {
#pragma unroll
      for (int ut = 0; ut < 4; ++ut)
        rA[ut] = *(const short8*)(rb + (size_t)(s + 2) * 8192 + ut * 512);
    }
    // step s+1
#pragma unroll
    for (int lt = 0; lt < 4; ++lt)
      xf[lt] = *(const short8*)(xb + lt * (16 * XPR) + (s + 1) * 32);
#pragma unroll
    for (int ut = 0; ut < 4; ++ut)
#pragma unroll
      for (int lt = 0; lt < 4; ++lt)
        acc[ut][lt] = __builtin_amdgcn_mfma_f32_16x16x32_bf16(
            rB[ut], xf[lt], acc[ut][lt], 0, 0, 0);
  }

  // Epilogue: D layout col(l)=lane&15, row(u)=(lane>>4)*4+reg -> lane holds
  // 4 consecutive u at fixed l => float4 store into row-major Z[l][u].
  float* Z = out + SZ_S + SZ_R;
  const int ug = fj << 2;
  float pmax[4][4];
#pragma unroll
  for (int ut = 0; ut < 4; ++ut)
#pragma unroll
    for (int r = 0; r < 4; ++r) pmax[ut][r] = -INFINITY;

#pragma unroll
  for (int lt = 0; lt < 4; ++lt) {
    const int l = l0 + wl * 64 + lt * 16 + fl;
    if (l < LOUT) {
      float* zrow = Z + ((size_t)n * LOUT + l) * U_ + u0 + wu * 64 + ug;
#pragma unroll
      for (int ut = 0; ut < 4; ++ut) {
        f32x4 v = acc[ut][lt];
        *(f32x4*)(zrow + ut * 16) = v;
#pragma unroll
        for (int r = 0; r < 4; ++r) pmax[ut][r] = fmaxf(pmax[ut][r], v[r]);
      }
    }
  }

#pragma unroll
  for (int off = 1; off < 16; off <<= 1)
#pragma unroll
    for (int ut = 0; ut < 4; ++ut)
#pragma unroll
      for (int r = 0; r < 4; ++r)
        pmax[ut][r] = fmaxf(pmax[ut][r], __shfl_xor(pmax[ut][r], off));

  if (fl == 0) {
    const int tn = n / F_;
    float* Sp = out + (size_t)tn * U_ + u0 + wu * 64 + ug;
#pragma unroll
    for (int ut = 0; ut < 4; ++ut)
#pragma unroll
      for (int r = 0; r < 4; ++r)
        atomicMaxF(Sp + ut * 16 + r, pmax[ut][r]);
  }
}

extern "C" void kernel_launch(void* const* d_in, const int* in_sizes, int n_in,
                              void* d_out, int out_size, void* d_ws, size_t ws_size,
                              hipStream_t stream) {
  const float* X       = (const float*)d_in[0];
  const float* P_logit = (const float*)d_in[1];
  const float* Q       = (const float*)d_in[2];
  float* out = (float*)d_out;

  unsigned short* Rt = (unsigned short*)d_ws;            // 256 KB
  const size_t rt_bytes = (size_t)RT_SHORTS * 2;
  unsigned short* Xp = (unsigned short*)((char*)d_ws + rt_bytes);
  // Xp: NIMG*XROWS*24 shorts (~19.5 MB) + 1 KB slack for the last block's
  // 8 KB LDS stage over-read (staged-but-never-read rows).

  hipMemsetAsync(Rt, 0, rt_bytes, stream);   // zero pad slots of Rt
  hipLaunchKernelGGL(prep_kernel, dim3(64), dim3(256), 0, stream,
                     P_logit, Q, out, Rt);
  int xthreads = NIMG * XROWS * 12;
  hipLaunchKernelGGL(xconv_kernel, dim3((xthreads + 255) / 256), dim3(256),
                     0, stream, X, (unsigned int*)Xp);
  dim3 grid(2, 8, NIMG);   // u-tiles, l-tiles, images
  hipLaunchKernelGGL(conv_kernel, grid, dim3(256), 0, stream, Xp, Rt, out);
}